// Round 2
// baseline (15464.586 us; speedup 1.0000x reference)
//
#include <hip/hip_runtime.h>
#include <hip/hip_bf16.h>
#include <math.h>

#define L 2
#define B 2
#define T 2048
#define C 512
#define H 8
#define FF 1024
#define HS 64
#define EPSV 1.1920929e-07f

typedef __hip_bfloat16 bf16;

__device__ __forceinline__ float b2f(bf16 x) { return __bfloat162float(x); }

// ---- dtype detection: g1 == ones. bf16 -> bits[0]=0x3F80 ; f32 -> bits[0]=0x0000 ----
__global__ void detect_k(const unsigned short* __restrict__ g1bits, int* __restrict__ flag) {
    if (threadIdx.x == 0 && blockIdx.x == 0)
        *flag = (g1bits[0] != (unsigned short)0x3F80u) ? 1 : 0;  // 1 = inputs are f32
}

// ---- normalize an input array to bf16 in ws ----
__global__ void conv_bf16_k(const void* __restrict__ in, bf16* __restrict__ out, int n,
                            const int* __restrict__ flag) {
    int i = blockIdx.x * blockDim.x + threadIdx.x;
    if (i >= n) return;
    if (*flag) out[i] = __float2bfloat16(((const float*)in)[i]);
    else       out[i] = ((const bf16*)in)[i];
}

// ---- normalize an input array to f32 in ws ----
__global__ void conv_f32_k(const void* __restrict__ in, float* __restrict__ out, int n,
                           const int* __restrict__ flag) {
    int i = blockIdx.x * blockDim.x + threadIdx.x;
    if (i >= n) return;
    if (*flag) out[i] = ((const float*)in)[i];
    else       out[i] = b2f(((const bf16*)in)[i]);
}

// ---- write final output in the harness's dtype ----
__global__ void write_out_k(const float* __restrict__ in, void* __restrict__ out, int n,
                            const int* __restrict__ flag) {
    int i = blockIdx.x * blockDim.x + threadIdx.x;
    if (i >= n) return;
    if (*flag) ((float*)out)[i] = in[i];
    else       ((bf16*)out)[i] = __float2bfloat16(in[i]);
}

// ---- RMSNorm: one block (256 thr) per row of C=512 ----
__global__ void rmsnorm_k(const float* __restrict__ x, const bf16* __restrict__ g,
                          float* __restrict__ y) {
    int row = blockIdx.x;  // B*T rows
    const float* xr = x + (size_t)row * C;
    float* yr = y + (size_t)row * C;
    int tid = threadIdx.x;
    float v0 = xr[tid], v1 = xr[tid + 256];
    __shared__ float red[256];
    red[tid] = v0 * v0 + v1 * v1;
    __syncthreads();
    for (int s = 128; s > 0; s >>= 1) {
        if (tid < s) red[tid] += red[tid + s];
        __syncthreads();
    }
    float scale = rsqrtf(red[0] / (float)C + EPSV);
    yr[tid] = v0 * scale * b2f(g[tid]);
    yr[tid + 256] = v1 * scale * b2f(g[tid + 256]);
}

// ---- fused Q/K/V projection: grid (T,H,B), block 64 (one wave, one d each) ----
__global__ void qkv_k(const float* __restrict__ qin, const float* __restrict__ kvin,
                      const bf16* __restrict__ Wq, const bf16* __restrict__ Wk,
                      const bf16* __restrict__ Wv,
                      float* __restrict__ q, float* __restrict__ k, float* __restrict__ v) {
    int t = blockIdx.x, h = blockIdx.y, b = blockIdx.z, d = threadIdx.x;
    const float* xq = qin + ((size_t)b * T + t) * C;
    const float* xkv = kvin + ((size_t)b * T + t) * C;
    const bf16* wq = Wq + (size_t)h * C * HS + d;
    const bf16* wk = Wk + (size_t)h * C * HS + d;
    const bf16* wv = Wv + (size_t)h * C * HS + d;
    float aq = 0.f, ak = 0.f, av = 0.f;
    for (int c = 0; c < C; c++) {
        float xqc = xq[c], xkvc = xkv[c];
        aq += xqc * b2f(wq[(size_t)c * HS]);
        ak += xkvc * b2f(wk[(size_t)c * HS]);
        av += xkvc * b2f(wv[(size_t)c * HS]);
    }
    size_t o = (((size_t)b * H + h) * T + t) * HS + d;
    q[o] = aq;
    k[o] = ak;
    v[o] = av;
}

// ---- attention: one block (256 thr) per (b,h,t); full score row in LDS ----
__global__ void attn_k(const float* __restrict__ q, const float* __restrict__ k,
                       const float* __restrict__ v, float* __restrict__ out, int causal) {
    int t = blockIdx.x, h = blockIdx.y, b = blockIdx.z;
    int tid = threadIdx.x;
    __shared__ float qs[HS];
    __shared__ float sc[T];
    __shared__ float red[256];
    size_t base = ((size_t)b * H + h) * T;
    if (tid < HS) qs[tid] = q[(base + t) * HS + tid];
    __syncthreads();
    int limit = causal ? (t + 1) : T;

    // scores + max
    float lmax = -1e30f;
    for (int s = tid; s < limit; s += 256) {
        const float* kr = k + (base + s) * HS;
        float dot = 0.f;
#pragma unroll
        for (int d = 0; d < HS; d++) dot += qs[d] * kr[d];
        dot *= 0.125f;  // 1/sqrt(64)
        sc[s] = dot;
        lmax = fmaxf(lmax, dot);
    }
    red[tid] = lmax;
    __syncthreads();
    for (int s2 = 128; s2 > 0; s2 >>= 1) {
        if (tid < s2) red[tid] = fmaxf(red[tid], red[tid + s2]);
        __syncthreads();
    }
    float m = red[0];
    __syncthreads();

    // exp + sum
    float lsum = 0.f;
    for (int s = tid; s < limit; s += 256) {
        float e = expf(sc[s] - m);
        sc[s] = e;
        lsum += e;
    }
    red[tid] = lsum;
    __syncthreads();
    for (int s2 = 128; s2 > 0; s2 >>= 1) {
        if (tid < s2) red[tid] += red[tid + s2];
        __syncthreads();
    }
    float inv = 1.0f / red[0];
    __syncthreads();

    // P @ V
    int d = tid & (HS - 1);
    int chunk = tid >> 6;  // 0..3
    float acc = 0.f;
    for (int s = chunk; s < limit; s += 4) {
        acc += sc[s] * v[(base + s) * HS + d];
    }
    red[tid] = acc;
    __syncthreads();
    if (tid < HS) {
        float r = red[d] + red[64 + d] + red[128 + d] + red[192 + d];
        out[(base + t) * HS + d] = r * inv;
    }
}

// ---- output projection + bias + residual add into t ----
__global__ void proj_res_k(const float* __restrict__ attnout, const bf16* __restrict__ Wo,
                           const bf16* __restrict__ bo, float* __restrict__ tbuf) {
    int idx = blockIdx.x * blockDim.x + threadIdx.x;  // B*T*C
    int c = idx & (C - 1);
    int bt = idx >> 9;
    int b = bt >> 11;
    int t = bt & (T - 1);
    float acc = b2f(bo[c]);
    for (int cp = 0; cp < C; cp++) {
        int hh = cp >> 6;
        int d = cp & 63;
        float xv = attnout[(((size_t)b * H + hh) * T + t) * HS + d];
        acc += xv * b2f(Wo[(size_t)cp * C + c]);
    }
    tbuf[idx] += acc;
}

// ---- FFN ----
__global__ void ffn1_k(const float* __restrict__ x, const bf16* __restrict__ W1,
                       const bf16* __restrict__ b1, float* __restrict__ h1) {
    int idx = blockIdx.x * blockDim.x + threadIdx.x;  // B*T*FF
    int f = idx & (FF - 1);
    int bt = idx >> 10;
    float acc = b2f(b1[f]);
    const float* xr = x + (size_t)bt * C;
    const bf16* w = W1 + f;
    for (int c = 0; c < C; c++) acc += xr[c] * b2f(w[(size_t)c * FF]);
    h1[idx] = 0.5f * acc * (1.0f + erff(acc * 0.70710678118654752f));
}

__global__ void ffn2_k(const float* __restrict__ h1, const bf16* __restrict__ W2,
                       const bf16* __restrict__ b2, float* __restrict__ tbuf) {
    int idx = blockIdx.x * blockDim.x + threadIdx.x;  // B*T*C
    int c = idx & (C - 1);
    int bt = idx >> 9;
    float acc = b2f(b2[c]);
    const float* hr = h1 + (size_t)bt * FF;
    const bf16* w = W2 + c;
    for (int f = 0; f < FF; f++) acc += hr[f] * b2f(w[(size_t)f * C]);
    tbuf[idx] += acc;
}

extern "C" void kernel_launch(void* const* d_in, const int* in_sizes, int n_in,
                              void* d_out, int out_size, void* d_ws, size_t ws_size,
                              hipStream_t stream) {
    const int BTC = B * T * C;   // 2,097,152
    const int BTF = B * T * FF;  // 4,194,304
    const int WH = L * H * C * HS;  // 524,288 (per Wq/Wk/Wv array, both layers)
    const int WO = L * C * C;       // 524,288
    const int W1S = L * C * FF;     // 1,048,576
    const int W2S = L * FF * C;     // 1,048,576

    // ---- workspace layout ----
    char* wsb = (char*)d_ws;
    int* flag = (int*)wsb;
    bf16* bw = (bf16*)(wsb + 16);  // bf16 weight region
    bf16* cWq_s = bw;            bf16* cWk_s = cWq_s + WH;   bf16* cWv_s = cWk_s + WH;
    bf16* cWo_s = cWv_s + WH;    bf16* cbo_s = cWo_s + WO;
    bf16* cWq_x = cbo_s + L * C; bf16* cWk_x = cWq_x + WH;   bf16* cWv_x = cWk_x + WH;
    bf16* cWo_x = cWv_x + WH;    bf16* cbo_x = cWo_x + WO;
    bf16* cW1 = cbo_x + L * C;   bf16* cb1 = cW1 + W1S;
    bf16* cW2 = cb1 + L * FF;    bf16* cb2 = cW2 + W2S;
    bf16* cg1 = cb2 + L * C;     bf16* cg2 = cg1 + L * C;
    bf16* cg3 = cg2 + L * C;     bf16* cg4 = cg3 + L * C;
    bf16* bw_end = cg4 + L * C;
    size_t f32_off = (((char*)bw_end - wsb) + 255) & ~(size_t)255;
    float* t_buf = (float*)(wsb + f32_off);  // BTC
    float* hid = t_buf + BTC;                // BTC
    float* n1 = hid + BTC;                   // BTC
    float* n2 = n1 + BTC;                    // BTC
    float* q = n2 + BTC;                     // BTC
    float* k = q + BTC;                      // BTC
    float* v = k + BTC;                      // BTC
    float* attnout = v + BTC;                // BTC
    float* h1 = q;                           // BTF, aliases q+k (dead during FFN)

    dim3 blk256(256);
    dim3 thb(T, H, B);
    auto g = [](int n) { return dim3((n + 255) / 256); };

    detect_k<<<1, 64, 0, stream>>>((const unsigned short*)d_in[16], flag);

    // normalize weights -> bf16 in ws
    conv_bf16_k<<<g(WH), blk256, 0, stream>>>(d_in[2], cWq_s, WH, flag);
    conv_bf16_k<<<g(WH), blk256, 0, stream>>>(d_in[3], cWk_s, WH, flag);
    conv_bf16_k<<<g(WH), blk256, 0, stream>>>(d_in[4], cWv_s, WH, flag);
    conv_bf16_k<<<g(WO), blk256, 0, stream>>>(d_in[5], cWo_s, WO, flag);
    conv_bf16_k<<<g(L * C), blk256, 0, stream>>>(d_in[6], cbo_s, L * C, flag);
    conv_bf16_k<<<g(WH), blk256, 0, stream>>>(d_in[7], cWq_x, WH, flag);
    conv_bf16_k<<<g(WH), blk256, 0, stream>>>(d_in[8], cWk_x, WH, flag);
    conv_bf16_k<<<g(WH), blk256, 0, stream>>>(d_in[9], cWv_x, WH, flag);
    conv_bf16_k<<<g(WO), blk256, 0, stream>>>(d_in[10], cWo_x, WO, flag);
    conv_bf16_k<<<g(L * C), blk256, 0, stream>>>(d_in[11], cbo_x, L * C, flag);
    conv_bf16_k<<<g(W1S), blk256, 0, stream>>>(d_in[12], cW1, W1S, flag);
    conv_bf16_k<<<g(L * FF), blk256, 0, stream>>>(d_in[13], cb1, L * FF, flag);
    conv_bf16_k<<<g(W2S), blk256, 0, stream>>>(d_in[14], cW2, W2S, flag);
    conv_bf16_k<<<g(L * C), blk256, 0, stream>>>(d_in[15], cb2, L * C, flag);
    conv_bf16_k<<<g(L * C), blk256, 0, stream>>>(d_in[16], cg1, L * C, flag);
    conv_bf16_k<<<g(L * C), blk256, 0, stream>>>(d_in[17], cg2, L * C, flag);
    conv_bf16_k<<<g(L * C), blk256, 0, stream>>>(d_in[18], cg3, L * C, flag);
    conv_bf16_k<<<g(L * C), blk256, 0, stream>>>(d_in[19], cg4, L * C, flag);

    // activations -> f32
    conv_f32_k<<<g(BTC), blk256, 0, stream>>>(d_in[0], hid, BTC, flag);
    conv_f32_k<<<g(BTC), blk256, 0, stream>>>(d_in[1], t_buf, BTC, flag);

    for (int l = 0; l < L; l++) {
        const size_t wqkv_off = (size_t)l * H * C * HS;
        const size_t wo_off = (size_t)l * C * C;

        // --- masked self-attention ---
        rmsnorm_k<<<B * T, blk256, 0, stream>>>(t_buf, cg1 + l * C, n1);
        qkv_k<<<thb, 64, 0, stream>>>(n1, n1, cWq_s + wqkv_off, cWk_s + wqkv_off,
                                      cWv_s + wqkv_off, q, k, v);
        attn_k<<<thb, blk256, 0, stream>>>(q, k, v, attnout, 1);
        proj_res_k<<<g(BTC), blk256, 0, stream>>>(attnout, cWo_s + wo_off, cbo_s + l * C, t_buf);

        // --- cross-attention ---
        rmsnorm_k<<<B * T, blk256, 0, stream>>>(t_buf, cg3 + l * C, n1);
        rmsnorm_k<<<B * T, blk256, 0, stream>>>(hid, cg2 + l * C, n2);
        qkv_k<<<thb, 64, 0, stream>>>(n1, n2, cWq_x + wqkv_off, cWk_x + wqkv_off,
                                      cWv_x + wqkv_off, q, k, v);
        attn_k<<<thb, blk256, 0, stream>>>(q, k, v, attnout, 0);
        proj_res_k<<<g(BTC), blk256, 0, stream>>>(attnout, cWo_x + wo_off, cbo_x + l * C, t_buf);

        // --- FFN ---
        rmsnorm_k<<<B * T, blk256, 0, stream>>>(t_buf, cg4 + l * C, n1);
        ffn1_k<<<g(BTF), blk256, 0, stream>>>(n1, cW1 + (size_t)l * C * FF, cb1 + l * FF, h1);
        ffn2_k<<<g(BTC), blk256, 0, stream>>>(h1, cW2 + (size_t)l * FF * C, cb2 + l * C, t_buf);
    }

    write_out_k<<<g(BTC), blk256, 0, stream>>>(t_buf, d_out, BTC, flag);
}

// Round 3
// 899.552 us; speedup vs baseline: 17.1914x; 17.1914x over previous
//
#include <hip/hip_runtime.h>
#include <hip/hip_bf16.h>
#include <math.h>

#define L 2
#define B 2
#define T 2048
#define C 512
#define H 8
#define FF 1024
#define HS 64
#define EPSV 1.1920929e-07f

typedef __hip_bfloat16 bf16;
typedef __attribute__((ext_vector_type(8))) short short8;
typedef __attribute__((ext_vector_type(8))) unsigned short ushort8v;
typedef __attribute__((ext_vector_type(4))) float f32x4;

__device__ __forceinline__ float b2f(bf16 x) { return __bfloat162float(x); }

// ---- dtype detection: g1 == ones. bf16 -> bits[0]=0x3F80 ; f32 -> bits[0]=0x0000 ----
__global__ void detect_k(const unsigned short* __restrict__ g1bits, int* __restrict__ flag) {
    if (threadIdx.x == 0 && blockIdx.x == 0)
        *flag = (g1bits[0] != (unsigned short)0x3F80u) ? 1 : 0;  // 1 = inputs are f32
}

__device__ __forceinline__ float ld_in(const void* p, size_t i, int fl) {
    return fl ? ((const float*)p)[i] : b2f(((const bf16*)p)[i]);
}

// ---- plain normalize to bf16 (biases/gains) ----
__global__ void conv_bf16_k(const void* __restrict__ in, bf16* __restrict__ out, int n,
                            const int* __restrict__ flag) {
    int i = blockIdx.x * blockDim.x + threadIdx.x;
    if (i >= n) return;
    out[i] = __float2bfloat16(ld_in(in, i, *flag));
}

// ---- normalize to f32 (activations) ----
__global__ void conv_f32_k(const void* __restrict__ in, float* __restrict__ out, int n,
                           const int* __restrict__ flag) {
    int i = blockIdx.x * blockDim.x + threadIdx.x;
    if (i >= n) return;
    out[i] = ld_in(in, i, *flag);
}

// ---- final output in harness dtype ----
__global__ void write_out_k(const float* __restrict__ in, void* __restrict__ out, int n,
                            const int* __restrict__ flag) {
    int i = blockIdx.x * blockDim.x + threadIdx.x;
    if (i >= n) return;
    if (*flag) ((float*)out)[i] = in[i];
    else       ((bf16*)out)[i] = __float2bfloat16(in[i]);
}

// ---- W{q,k,v}[l,h,c,d] -> fused QKV^T [l][1536][512] bf16, row n = projOff+h*64+d ----
__global__ void tr_qkv_k(const void* __restrict__ src, bf16* __restrict__ dst, int projOff,
                         const int* __restrict__ flag) {
    int j = blockIdx.x * blockDim.x + threadIdx.x;  // L*H*HS*C
    int fl = *flag;
    int c = j & 511;
    int nn = (j >> 9) & 511;     // h*64+d
    int l = j >> 18;
    int h = nn >> 6, d = nn & 63;
    size_t si = (((size_t)(l * H + h) * C + c) * HS + d);
    dst[(size_t)l * (3 * C * C) + (size_t)(projOff + nn) * C + c] =
        __float2bfloat16(ld_in(src, si, fl));
}

// ---- W[l][K][N] -> W^T [l][N][K] bf16 (dst-order enumeration) ----
__global__ void tr_mat_k(const void* __restrict__ src, bf16* __restrict__ dst, int kbits,
                         int nbits, const int* __restrict__ flag) {
    int j = blockIdx.x * blockDim.x + threadIdx.x;  // L << (kbits+nbits)
    int fl = *flag;
    int Kd = 1 << kbits, Nd = 1 << nbits;
    int c = j & (Kd - 1);
    int n = (j >> kbits) & (Nd - 1);
    int l = j >> (kbits + nbits);
    size_t si = ((size_t)l << (kbits + nbits)) + ((size_t)c << nbits) + n;
    dst[j] = __float2bfloat16(ld_in(src, si, fl));
}

// ---- RMSNorm: f32 in, bf16 out; one block per row ----
__global__ void rmsnorm_k(const float* __restrict__ x, const bf16* __restrict__ g,
                          bf16* __restrict__ y) {
    int row = blockIdx.x;
    int tid = threadIdx.x;
    const float* xr = x + (size_t)row * C;
    float v0 = xr[tid], v1 = xr[tid + 256];
    __shared__ float red[256];
    red[tid] = v0 * v0 + v1 * v1;
    __syncthreads();
    for (int s = 128; s > 0; s >>= 1) {
        if (tid < s) red[tid] += red[tid + s];
        __syncthreads();
    }
    float sc = rsqrtf(red[0] / (float)C + EPSV);
    y[(size_t)row * C + tid] = __float2bfloat16(v0 * sc * b2f(g[tid]));
    y[(size_t)row * C + tid + 256] = __float2bfloat16(v1 * sc * b2f(g[tid + 256]));
}

// ---- MFMA GEMM: D[M,N] = A[M,K] (bf16 rm) x Bt[N,K]^T (bf16 rm, k-contig) ----
// EP 0: out_bf16 = D              EP 1: resid_f32 += D + bias
// EP 2: out_bf16 = gelu(D + bias)
template <int EP>
__global__ __launch_bounds__(256) void gemm_bt_k(const bf16* __restrict__ A,
                                                 const bf16* __restrict__ Bt,
                                                 const bf16* __restrict__ bias,
                                                 float* __restrict__ resid,
                                                 bf16* __restrict__ out, int M, int N, int K,
                                                 int ldOut) {
    __shared__ unsigned short As[128 * 32];
    __shared__ unsigned short Bs[128 * 32];
    int tid = threadIdx.x;
    int lane = tid & 63, wave = tid >> 6;
    int wr = wave >> 1, wc = wave & 1;
    int quad = lane >> 4, rA = lane & 15;
    int m0 = blockIdx.y * 128, n0 = blockIdx.x * 128;
    const unsigned short* Au = (const unsigned short*)A;
    const unsigned short* Bu = (const unsigned short*)Bt;
    f32x4 zf = {0.f, 0.f, 0.f, 0.f};
    f32x4 acc[4][4];
#pragma unroll
    for (int i = 0; i < 4; i++)
#pragma unroll
        for (int j = 0; j < 4; j++) acc[i][j] = zf;

    for (int k0 = 0; k0 < K; k0 += 32) {
#pragma unroll
        for (int it = 0; it < 2; it++) {
            int unit = it * 256 + tid;
            int row = unit >> 2, s = unit & 3;
            int sw = s ^ ((row >> 1) & 3);
            *(ushort8v*)(As + row * 32 + sw * 8) =
                *(const ushort8v*)(Au + (size_t)(m0 + row) * K + k0 + s * 8);
            *(ushort8v*)(Bs + row * 32 + sw * 8) =
                *(const ushort8v*)(Bu + (size_t)(n0 + row) * K + k0 + s * 8);
        }
        __syncthreads();
        short8 af[4], bfr[4];
#pragma unroll
        for (int mi = 0; mi < 4; mi++) {
            int r = wr * 64 + mi * 16 + rA;
            int sw = quad ^ ((r >> 1) & 3);
            af[mi] = *(const short8*)(As + r * 32 + sw * 8);
        }
#pragma unroll
        for (int ni = 0; ni < 4; ni++) {
            int r = wc * 64 + ni * 16 + rA;
            int sw = quad ^ ((r >> 1) & 3);
            bfr[ni] = *(const short8*)(Bs + r * 32 + sw * 8);
        }
#pragma unroll
        for (int mi = 0; mi < 4; mi++)
#pragma unroll
            for (int ni = 0; ni < 4; ni++)
                acc[mi][ni] =
                    __builtin_amdgcn_mfma_f32_16x16x32_bf16(af[mi], bfr[ni], acc[mi][ni], 0, 0, 0);
        __syncthreads();
    }

#pragma unroll
    for (int mi = 0; mi < 4; mi++) {
#pragma unroll
        for (int ni = 0; ni < 4; ni++) {
            int colg = n0 + wc * 64 + ni * 16 + rA;
            float bv = (EP == 0) ? 0.f : b2f(bias[colg]);
#pragma unroll
            for (int r2 = 0; r2 < 4; r2++) {
                int rowg = m0 + wr * 64 + mi * 16 + quad * 4 + r2;
                float v = acc[mi][ni][r2];
                if (EP == 0) {
                    out[(size_t)rowg * ldOut + colg] = __float2bfloat16(v);
                } else if (EP == 1) {
                    resid[(size_t)rowg * ldOut + colg] += v + bv;
                } else {
                    float u = v + bv;
                    float ge = 0.5f * u * (1.f + erff(u * 0.70710678118654752f));
                    out[(size_t)rowg * ldOut + colg] = __float2bfloat16(ge);
                }
            }
        }
    }
}

// ---- flash attention, MFMA: block = (qtile 64, h, b), 256 thr = 4 waves ----
// qkv: [B*T, 1536] bf16 (q | k | v), out: [B*T, 512] bf16 (col h*64+d)
__global__ __launch_bounds__(256) void attn_mfma_k(const bf16* __restrict__ qkv,
                                                   bf16* __restrict__ attnout, int causal) {
    __shared__ unsigned short Qs[64 * 64], Ks[64 * 64], Vt[64 * 64], Ps[64 * 64];
    bf16* Psb = (bf16*)Ps;
    int qt = blockIdx.x, h = blockIdx.y, b = blockIdx.z;
    int tid = threadIdx.x;
    int lane = tid & 63, w = tid >> 6;
    int quad = lane >> 4, l15 = lane & 15;
    const unsigned short* qk = (const unsigned short*)qkv;
    size_t rowbase = (size_t)b * T;
    int qoff = h * HS, koff = C + h * HS, voff = 2 * C + h * HS;

    // stage Q tile (rows qt*64 ..), xor-swizzled segments
#pragma unroll
    for (int it = 0; it < 2; it++) {
        int unit = it * 256 + tid;
        int r = unit >> 3, seg = unit & 7;
        ushort8v qv = *(const ushort8v*)(qk + (rowbase + qt * 64 + r) * 1536 + qoff + seg * 8);
        *(ushort8v*)(Qs + r * 64 + ((seg ^ (r & 7)) * 8)) = qv;
    }

    f32x4 zf = {0.f, 0.f, 0.f, 0.f};
    f32x4 oacc[4];
#pragma unroll
    for (int i = 0; i < 4; i++) oacc[i] = zf;
    float m_run[4], l_run[4];
#pragma unroll
    for (int i = 0; i < 4; i++) {
        m_run[i] = -1e30f;
        l_run[i] = 0.f;
    }

    int nT = causal ? (qt + 1) : (T / 64);
    for (int st = 0; st < nT; st++) {
        __syncthreads();  // Qs ready (first iter) / prior PV done with Ks,Vt,Ps
#pragma unroll
        for (int it = 0; it < 2; it++) {
            int unit = it * 256 + tid;
            int r = unit >> 3, seg = unit & 7;
            ushort8v kv8 = *(const ushort8v*)(qk + (rowbase + st * 64 + r) * 1536 + koff + seg * 8);
            *(ushort8v*)(Ks + r * 64 + ((seg ^ (r & 7)) * 8)) = kv8;
            ushort8v vv8 = *(const ushort8v*)(qk + (rowbase + st * 64 + r) * 1536 + voff + seg * 8);
#pragma unroll
            for (int j = 0; j < 8; j++) {
                int d = seg * 8 + j;
                Vt[d * 64 + (((r >> 3) ^ (d & 7)) * 8) + (r & 7)] = vv8[j];
            }
        }
        __syncthreads();  // tiles ready

        // S = Q K^T : wave w -> q rows [w*16, w*16+16), 4 ni tiles of 16 s-cols
        f32x4 sacc[4];
#pragma unroll
        for (int i = 0; i < 4; i++) sacc[i] = zf;
#pragma unroll
        for (int kk = 0; kk < 2; kk++) {
            int qrow = w * 16 + l15;
            short8 aq = *(const short8*)(Qs + qrow * 64 + (((kk * 4 + quad) ^ (qrow & 7)) * 8));
#pragma unroll
            for (int ni = 0; ni < 4; ni++) {
                int srow = ni * 16 + l15;
                short8 bk = *(const short8*)(Ks + srow * 64 + (((kk * 4 + quad) ^ (srow & 7)) * 8));
                sacc[ni] = __builtin_amdgcn_mfma_f32_16x16x32_bf16(aq, bk, sacc[ni], 0, 0, 0);
            }
        }

        // online softmax in C/D layout: S[q=w*16+quad*4+reg][s=ni*16+l15]
#pragma unroll
        for (int reg = 0; reg < 4; reg++) {
            int qg = qt * 64 + w * 16 + quad * 4 + reg;
            float mold = m_run[reg];
            float sv[4];
            float tmax = -1e30f;
#pragma unroll
            for (int ni = 0; ni < 4; ni++) {
                float s = sacc[ni][reg] * 0.125f;  // 1/sqrt(HS)
                int sg = st * 64 + ni * 16 + l15;
                if (causal && sg > qg) s = -1e30f;
                sv[ni] = s;
                tmax = fmaxf(tmax, s);
            }
            for (int mk = 1; mk < 16; mk <<= 1) tmax = fmaxf(tmax, __shfl_xor(tmax, mk, 64));
            float mnew = fmaxf(mold, tmax);
            float alpha = __expf(mold - mnew);
            float psum = 0.f;
            int q_l = w * 16 + quad * 4 + reg;
#pragma unroll
            for (int ni = 0; ni < 4; ni++) {
                float p = __expf(sv[ni] - mnew);
                psum += p;
                int s_l = ni * 16 + l15;
                Psb[q_l * 64 + (((s_l >> 3) ^ (q_l & 7)) * 8) + (s_l & 7)] = __float2bfloat16(p);
            }
            for (int mk = 1; mk < 16; mk <<= 1) psum += __shfl_xor(psum, mk, 64);
            l_run[reg] = l_run[reg] * alpha + psum;
            m_run[reg] = mnew;
#pragma unroll
            for (int dj = 0; dj < 4; dj++) oacc[dj][reg] *= alpha;
        }
        __syncthreads();  // Ps ready

        // O += P V : A = P rows [w*16..), B^T = Vt
#pragma unroll
        for (int kk = 0; kk < 2; kk++) {
            int prow = w * 16 + l15;
            short8 ap = *(const short8*)(Ps + prow * 64 + (((kk * 4 + quad) ^ (prow & 7)) * 8));
#pragma unroll
            for (int dj = 0; dj < 4; dj++) {
                int drow = dj * 16 + l15;
                short8 bv8 = *(const short8*)(Vt + drow * 64 + (((kk * 4 + quad) ^ (drow & 7)) * 8));
                oacc[dj] = __builtin_amdgcn_mfma_f32_16x16x32_bf16(ap, bv8, oacc[dj], 0, 0, 0);
            }
        }
    }

#pragma unroll
    for (int dj = 0; dj < 4; dj++) {
        int d = dj * 16 + l15;
#pragma unroll
        for (int reg = 0; reg < 4; reg++) {
            int q = w * 16 + quad * 4 + reg;
            float o = oacc[dj][reg] / l_run[reg];
            attnout[(rowbase + qt * 64 + q) * C + h * HS + d] = __float2bfloat16(o);
        }
    }
}

extern "C" void kernel_launch(void* const* d_in, const int* in_sizes, int n_in,
                              void* d_out, int out_size, void* d_ws, size_t ws_size,
                              hipStream_t stream) {
    const int BTC = B * T * C;       // 2,097,152
    const int BTF = B * T * FF;      // 4,194,304
    const int QKVW = L * H * C * HS; // 524,288 per source array
    const int QKVT = L * 3 * C * C;  // 1,572,864 fused
    const int WO = L * C * C;        // 524,288
    const int W12 = L * C * FF;      // 1,048,576

    char* wsb = (char*)d_ws;
    int* flag = (int*)wsb;
    bf16* cur = (bf16*)(wsb + 256);
    bf16* cQKVs = cur;            cur += QKVT;
    bf16* cQKVx = cur;            cur += QKVT;
    bf16* cWoTs = cur;            cur += WO;
    bf16* cWoTx = cur;            cur += WO;
    bf16* cW1T = cur;             cur += W12;
    bf16* cW2T = cur;             cur += W12;
    bf16* cbo_s = cur;            cur += L * C;
    bf16* cbo_x = cur;            cur += L * C;
    bf16* cb1 = cur;              cur += L * FF;
    bf16* cb2 = cur;              cur += L * C;
    bf16* cg1 = cur;              cur += L * C;
    bf16* cg2 = cur;              cur += L * C;
    bf16* cg3 = cur;              cur += L * C;
    bf16* cg4 = cur;              cur += L * C;
    bf16* n1 = cur;               cur += BTC;
    bf16* n2 = cur;               cur += BTC;
    bf16* qkvbuf = cur;           cur += B * T * 3 * C;
    bf16* attnout = cur;          cur += BTC;
    bf16* h1buf = cur;            cur += BTF;
    size_t f32_off = (((char*)cur - wsb) + 255) & ~(size_t)255;
    float* t_buf = (float*)(wsb + f32_off);
    float* hid = t_buf + BTC;

    dim3 blk256(256);
    auto g = [](int n) { return dim3((n + 255) / 256); };

    detect_k<<<1, 64, 0, stream>>>((const unsigned short*)d_in[16], flag);

    // weights -> transposed bf16
    tr_qkv_k<<<g(QKVW), blk256, 0, stream>>>(d_in[2], cQKVs, 0, flag);
    tr_qkv_k<<<g(QKVW), blk256, 0, stream>>>(d_in[3], cQKVs, 512, flag);
    tr_qkv_k<<<g(QKVW), blk256, 0, stream>>>(d_in[4], cQKVs, 1024, flag);
    tr_qkv_k<<<g(QKVW), blk256, 0, stream>>>(d_in[7], cQKVx, 0, flag);
    tr_qkv_k<<<g(QKVW), blk256, 0, stream>>>(d_in[8], cQKVx, 512, flag);
    tr_qkv_k<<<g(QKVW), blk256, 0, stream>>>(d_in[9], cQKVx, 1024, flag);
    tr_mat_k<<<g(WO), blk256, 0, stream>>>(d_in[5], cWoTs, 9, 9, flag);
    tr_mat_k<<<g(WO), blk256, 0, stream>>>(d_in[10], cWoTx, 9, 9, flag);
    tr_mat_k<<<g(W12), blk256, 0, stream>>>(d_in[12], cW1T, 9, 10, flag);
    tr_mat_k<<<g(W12), blk256, 0, stream>>>(d_in[14], cW2T, 10, 9, flag);
    conv_bf16_k<<<g(L * C), blk256, 0, stream>>>(d_in[6], cbo_s, L * C, flag);
    conv_bf16_k<<<g(L * C), blk256, 0, stream>>>(d_in[11], cbo_x, L * C, flag);
    conv_bf16_k<<<g(L * FF), blk256, 0, stream>>>(d_in[13], cb1, L * FF, flag);
    conv_bf16_k<<<g(L * C), blk256, 0, stream>>>(d_in[15], cb2, L * C, flag);
    conv_bf16_k<<<g(L * C), blk256, 0, stream>>>(d_in[16], cg1, L * C, flag);
    conv_bf16_k<<<g(L * C), blk256, 0, stream>>>(d_in[17], cg2, L * C, flag);
    conv_bf16_k<<<g(L * C), blk256, 0, stream>>>(d_in[18], cg3, L * C, flag);
    conv_bf16_k<<<g(L * C), blk256, 0, stream>>>(d_in[19], cg4, L * C, flag);

    conv_f32_k<<<g(BTC), blk256, 0, stream>>>(d_in[0], hid, BTC, flag);
    conv_f32_k<<<g(BTC), blk256, 0, stream>>>(d_in[1], t_buf, BTC, flag);

    const int M = B * T;  // 4096
    dim3 attngrid(T / 64, H, B);

    for (int l = 0; l < L; l++) {
        bf16* qkvW_s = cQKVs + (size_t)l * 3 * C * C;
        bf16* qkvW_x = cQKVx + (size_t)l * 3 * C * C;
        bf16* woT_s = cWoTs + (size_t)l * C * C;
        bf16* woT_x = cWoTx + (size_t)l * C * C;
        bf16* w1T = cW1T + (size_t)l * C * FF;
        bf16* w2T = cW2T + (size_t)l * FF * C;

        // --- masked self-attention ---
        rmsnorm_k<<<M, blk256, 0, stream>>>(t_buf, cg1 + l * C, n1);
        gemm_bt_k<0><<<dim3(12, 32), blk256, 0, stream>>>(n1, qkvW_s, nullptr, nullptr, qkvbuf,
                                                          M, 3 * C, C, 3 * C);
        attn_mfma_k<<<attngrid, blk256, 0, stream>>>(qkvbuf, attnout, 1);
        gemm_bt_k<1><<<dim3(4, 32), blk256, 0, stream>>>(attnout, woT_s, cbo_s + l * C, t_buf,
                                                         nullptr, M, C, C, C);

        // --- cross-attention: Q from ln3(t), K/V from ln2(hidden) ---
        rmsnorm_k<<<M, blk256, 0, stream>>>(t_buf, cg3 + l * C, n1);
        rmsnorm_k<<<M, blk256, 0, stream>>>(hid, cg2 + l * C, n2);
        gemm_bt_k<0><<<dim3(4, 32), blk256, 0, stream>>>(n1, qkvW_x, nullptr, nullptr, qkvbuf,
                                                         M, C, C, 3 * C);
        gemm_bt_k<0><<<dim3(8, 32), blk256, 0, stream>>>(n2, qkvW_x + (size_t)C * C, nullptr,
                                                         nullptr, qkvbuf + C, M, 2 * C, C, 3 * C);
        attn_mfma_k<<<attngrid, blk256, 0, stream>>>(qkvbuf, attnout, 0);
        gemm_bt_k<1><<<dim3(4, 32), blk256, 0, stream>>>(attnout, woT_x, cbo_x + l * C, t_buf,
                                                         nullptr, M, C, C, C);

        // --- FFN ---
        rmsnorm_k<<<M, blk256, 0, stream>>>(t_buf, cg4 + l * C, n1);
        gemm_bt_k<2><<<dim3(8, 32), blk256, 0, stream>>>(n1, w1T, cb1 + l * FF, nullptr, h1buf,
                                                         M, FF, C, FF);
        gemm_bt_k<1><<<dim3(4, 32), blk256, 0, stream>>>(h1buf, w2T, cb2 + l * C, t_buf, nullptr,
                                                         M, C, FF, C);
    }

    write_out_k<<<g(BTC), blk256, 0, stream>>>(t_buf, d_out, BTC, flag);
}